// Round 9
// baseline (220.068 us; speedup 1.0000x reference)
//
#include <hip/hip_runtime.h>

#define Kst 256
#define Dd 256
#define Vv 50000
#define VPAD 50176
#define Tt 512
#define Bb 256
#define KP1 257
#define MD 512
#define NROWS (KP1*KP1)   // 66049
#define EPSf 1e-5f

#define VB2 196           // vocab blocks (256 v each)
#define NP1 (VB2*4)       // 784 part1 rows
#define NTR ((NROWS+31)/32)  // 2065 trans tiles
#define EMB 800           // em block ids [0,800): xcd-bijective (bid%8 = xcd)

typedef __attribute__((ext_vector_type(8))) short short8;
typedef __attribute__((ext_vector_type(4))) float f32x4;
typedef __attribute__((ext_vector_type(4))) unsigned u32x4;
typedef __attribute__((ext_vector_type(2))) unsigned u32x2;

__device__ __forceinline__ unsigned short f2bf(float f) {
    unsigned u = __builtin_bit_cast(unsigned, f);
    unsigned r = (u + 0x7fffu + ((u >> 16) & 1u)) >> 16;
    return (unsigned short)r;
}
__device__ __forceinline__ float bf2f(unsigned short u) {
    return __builtin_bit_cast(float, ((unsigned)u) << 16);
}
// truncating pack (MFMA inputs only)
__device__ __forceinline__ unsigned bfpack(float lo, float hi) {
    return __builtin_amdgcn_perm(__builtin_bit_cast(unsigned, hi),
                                 __builtin_bit_cast(unsigned, lo), 0x07060302u);
}
// rounding pack (stores feeding final outputs)
__device__ __forceinline__ unsigned f2bf2(float lo, float hi) {
    return (unsigned)f2bf(lo) | ((unsigned)f2bf(hi) << 16);
}

// ---------------- K_hP: preprocessing (unchanged from round 8) ----------------
union HPU {
    struct { short ta[32][264]; float lsep[4][32][2]; float musig[32][2]; } g;
    struct { short pl[64][266]; } p;
};

__global__ __launch_bounds__(256) void k_hP(
    const float* __restrict__ lembs, const float* __restrict__ em_W,
    const float* __restrict__ em_bias, const float* __restrict__ em_g,
    const float* __restrict__ em_beta, unsigned short* __restrict__ h_bf,
    const float* __restrict__ tlembs, const float* __restrict__ tm_W,
    float* __restrict__ P0, float* __restrict__ P1,
    const float* __restrict__ td_W, const float* __restrict__ tn_g,
    const float* __restrict__ tn_beta, const float* __restrict__ td_b,
    unsigned short* __restrict__ tdwg_bf, float* __restrict__ Gt,
    float* __restrict__ Bt, const float* __restrict__ dec_W,
    unsigned short* __restrict__ dwP)
{
    __shared__ HPU su;
    int bid = blockIdx.x;
    int tid = threadIdx.x, lane = tid & 63, wv = tid >> 6;
    int l15 = lane & 15, q = lane >> 4;

    if (bid >= 108) {
        // one (vb2, chunk) per block: coalesced 1KB loads, LDS transpose, coalesced 1KB stores
        int pb = bid - 108;                // 0..783
        int vb2 = pb >> 2, c = pb & 3;
        short (*pl)[266] = su.p.pl;
        int base_row = vb2*256 + c*64;
        #pragma unroll 4
        for (int i = 0; i < 16; ++i) {
            int row = wv*16 + i;
            int grow = base_row + row; if (grow > Vv-1) grow = Vv-1;
            float4 f = ((const float4*)(dec_W + (size_t)grow*Dd))[lane];
            u32x2 w; w.x = bfpack(f.x, f.y); w.y = bfpack(f.z, f.w);
            *(u32x2*)&pl[row][lane*4] = w;
        }
        __syncthreads();
        #pragma unroll
        for (int i = 0; i < 8; ++i) {
            short8 val = *(const short8*)&pl[(lane & 15)*4 + wv][i*32 + (lane >> 4)*8];
            *(short8*)(dwP + ((size_t)vb2*8192 + (size_t)i*1024
                              + (c*4 + wv)*64 + lane)*8) = val;
        }
        return;
    }

    if (bid >= 44) {
        int c = (bid - 44)*4 + wv;
        const float4* w4 = (const float4*)(td_W + (size_t)c*MD);
        const float4* g4 = (const float4*)tn_g;
        const float4* b4 = (const float4*)tn_beta;
        float sg = 0.f, sb = 0.f;
        short8 o;
        #pragma unroll
        for (int u = 0; u < 2; ++u) {
            int j4 = lane*2 + u;
            float4 w = w4[j4], g = g4[j4], bt = b4[j4];
            sg += w.x*g.x + w.y*g.y + w.z*g.z + w.w*g.w;
            sb += w.x*bt.x + w.y*bt.y + w.z*bt.z + w.w*bt.w;
            o[u*4+0] = (short)f2bf(w.x*g.x);
            o[u*4+1] = (short)f2bf(w.y*g.y);
            o[u*4+2] = (short)f2bf(w.z*g.z);
            o[u*4+3] = (short)f2bf(w.w*g.w);
        }
        {
            int wvv = c >> 6, l15v = (c >> 2) & 15, ctv = c & 3;
            int ksv = lane >> 2, qv = lane & 3;
            *(short8*)(tdwg_bf +
                ((((size_t)wvv*16 + ksv)*4 + ctv)*64 + (qv*16 + l15v))*8) = o;
        }
        #pragma unroll
        for (int dd = 32; dd > 0; dd >>= 1) {
            sg += __shfl_xor(sg, dd);
            sb += __shfl_xor(sb, dd);
        }
        if (lane == 0) { Gt[c] = sg; Bt[c] = sb + td_b[c]; }
        return;
    }

    short (*ta)[264] = su.g.ta;
    float (*lsep)[32][2] = su.g.lsep;
    float (*musig)[2] = su.g.musig;

    int job, r0, cb, koff, BK;
    const float* Arow; const float* Brow;
    if (bid < 8) {
        job = 0; r0 = bid*32; cb = 0; koff = 0; BK = Dd;
        Arow = lembs; Brow = em_W;
    } else {
        int b2 = bid - 8;
        int half = b2 / 18;
        int b3 = b2 % 18;
        job = 1 + half;
        r0 = (b3 >> 1) * 32;
        cb = (b3 & 1) * 256;
        koff = half * 256; BK = MD;
        Arow = tlembs; Brow = tm_W;
    }

    {
        int row = tid >> 3, seg = (tid & 7) * 32;
        int r = r0 + row;
        if (r > 256) r = 256;
        const float4* s4 = (const float4*)(Arow + (size_t)r*Dd + seg);
        #pragma unroll
        for (int u = 0; u < 4; ++u) {
            float4 f0 = s4[u*2], f1 = s4[u*2+1];
            u32x4 pk;
            pk.x = bfpack(f0.x, f0.y);
            pk.y = bfpack(f0.z, f0.w);
            pk.z = bfpack(f1.x, f1.y);
            pk.w = bfpack(f1.z, f1.w);
            *(short8*)&ta[row][seg + u*8] = __builtin_bit_cast(short8, pk);
        }
    }
    __syncthreads();

    const float* bptr[4];
    #pragma unroll
    for (int ct = 0; ct < 4; ++ct) {
        int j = cb + wv*64 + ct*16 + l15;
        bptr[ct] = Brow + (size_t)j*BK + koff + q*8;
    }
    f32x4 acc[2][4];
    #pragma unroll
    for (int rt = 0; rt < 2; ++rt)
        #pragma unroll
        for (int ct = 0; ct < 4; ++ct)
            acc[rt][ct] = (f32x4){0.f,0.f,0.f,0.f};
    for (int ks = 0; ks < 8; ++ks) {
        short8 a0 = *(const short8*)&ta[ 0 + l15][ks*32 + q*8];
        short8 a1 = *(const short8*)&ta[16 + l15][ks*32 + q*8];
        short8 b[4];
        #pragma unroll
        for (int ct = 0; ct < 4; ++ct) {
            float4 f0 = *(const float4*)(bptr[ct] + ks*32);
            float4 f1 = *(const float4*)(bptr[ct] + ks*32 + 4);
            u32x4 pk;
            pk.x = bfpack(f0.x, f0.y);
            pk.y = bfpack(f0.z, f0.w);
            pk.z = bfpack(f1.x, f1.y);
            pk.w = bfpack(f1.z, f1.w);
            b[ct] = __builtin_bit_cast(short8, pk);
        }
        #pragma unroll
        for (int ct = 0; ct < 4; ++ct) {
            acc[0][ct] = __builtin_amdgcn_mfma_f32_16x16x32_bf16(a0, b[ct], acc[0][ct], 0,0,0);
            acc[1][ct] = __builtin_amdgcn_mfma_f32_16x16x32_bf16(a1, b[ct], acc[1][ct], 0,0,0);
        }
    }

    if (job != 0) {
        float* Pd = (job == 1) ? P0 : P1;
        #pragma unroll
        for (int rt = 0; rt < 2; ++rt) {
            #pragma unroll
            for (int reg = 0; reg < 4; ++reg) {
                int r = r0 + rt*16 + q*4 + reg;
                if (r < KP1) {
                    float* dst = Pd + (size_t)r*MD + cb + wv*64;
                    #pragma unroll
                    for (int ct = 0; ct < 4; ++ct)
                        dst[ct*16 + l15] = acc[rt][ct][reg];
                }
            }
        }
        return;
    }

    float bias_c[4];
    #pragma unroll
    for (int ct = 0; ct < 4; ++ct)
        bias_c[ct] = em_bias[wv*64 + ct*16 + l15];
    #pragma unroll
    for (int rt = 0; rt < 2; ++rt) {
        #pragma unroll
        for (int reg = 0; reg < 4; ++reg) {
            int r = r0 + rt*16 + q*4 + reg;
            #pragma unroll
            for (int ct = 0; ct < 4; ++ct) {
                float lv = lembs[(size_t)r*Dd + wv*64 + ct*16 + l15];
                acc[rt][ct][reg] = lv + fmaxf(acc[rt][ct][reg] + bias_c[ct], 0.f);
            }
        }
    }
    #pragma unroll
    for (int rt = 0; rt < 2; ++rt) {
        #pragma unroll
        for (int reg = 0; reg < 4; ++reg) {
            float s  = ((acc[rt][0][reg] + acc[rt][1][reg]) + (acc[rt][2][reg] + acc[rt][3][reg]));
            float ss = ((acc[rt][0][reg]*acc[rt][0][reg] + acc[rt][1][reg]*acc[rt][1][reg])
                      + (acc[rt][2][reg]*acc[rt][2][reg] + acc[rt][3][reg]*acc[rt][3][reg]));
            s  += __shfl_xor(s, 1);  ss += __shfl_xor(ss, 1);
            s  += __shfl_xor(s, 2);  ss += __shfl_xor(ss, 2);
            s  += __shfl_xor(s, 4);  ss += __shfl_xor(ss, 4);
            s  += __shfl_xor(s, 8);  ss += __shfl_xor(ss, 8);
            if (l15 == 0) {
                int rw = rt*16 + q*4 + reg;
                lsep[wv][rw][0] = s;
                lsep[wv][rw][1] = ss;
            }
        }
    }
    __syncthreads();
    if (tid < 32) {
        float s  = (lsep[0][tid][0] + lsep[1][tid][0]) + (lsep[2][tid][0] + lsep[3][tid][0]);
        float ss = (lsep[0][tid][1] + lsep[1][tid][1]) + (lsep[2][tid][1] + lsep[3][tid][1]);
        float mu = s * (1.f/Dd);
        musig[tid][0] = mu;
        musig[tid][1] = rsqrtf(ss*(1.f/Dd) - mu*mu + EPSf);
    }
    __syncthreads();
    float gl[4], bl[4];
    #pragma unroll
    for (int ct = 0; ct < 4; ++ct) {
        gl[ct] = em_g[wv*64 + ct*16 + l15];
        bl[ct] = em_beta[wv*64 + ct*16 + l15];
    }
    #pragma unroll
    for (int rt = 0; rt < 2; ++rt) {
        #pragma unroll
        for (int reg = 0; reg < 4; ++reg) {
            int rw = rt*16 + q*4 + reg;
            int r = r0 + rw;
            float mu = musig[rw][0], rs = musig[rw][1];
            unsigned short* dst = h_bf + (size_t)r*Dd + wv*64;
            #pragma unroll
            for (int ct = 0; ct < 4; ++ct)
                dst[ct*16 + l15] = f2bf((acc[rt][ct][reg] - mu)*rs*gl[ct] + bl[ct]);
        }
    }
}

// ---------------- K_emtrans: FUSED; em LSE partial = plain exp-sum into part1[784][256] ----------------
union SMemU {
    struct { short hs[64][264]; } em;
    struct { short th[32][520]; float musig[32][2]; float lsep[4][32][2]; } tr;
};

__global__ __launch_bounds__(256, 4) void k_emtrans(
    const unsigned short* __restrict__ dwP, const float* __restrict__ dec_b,
    const unsigned short* __restrict__ h_bf, float* __restrict__ part1,
    unsigned short* __restrict__ E2,
    const float* __restrict__ tlembs, const float* __restrict__ P0,
    const float* __restrict__ P1, const float* __restrict__ tm_bias,
    const short* __restrict__ tdwg_bf, const float* __restrict__ Gt,
    const float* __restrict__ Bt, float* __restrict__ lse_t,
    unsigned short* __restrict__ Td)
{
    __shared__ SMemU sm;
    int bid = blockIdx.x;
    int tid = threadIdx.x, lane = tid & 63, wv = tid >> 6;
    int l15 = lane & 15, q = lane >> 4;

    if (bid < EMB) {
        // ================= EM path =================
        int xcd = bid & 7, slot = bid >> 3;
        int g2 = slot >> 2, kg = slot & 3;
        int vb = g2*8 + xcd;
        if (vb >= VB2) return;
        short (*hs)[264] = sm.em.hs;

        {
            int row = tid >> 2, c0 = (tid & 3) * 64;
            const short8* src = (const short8*)(h_bf + (size_t)(kg*64 + row)*Dd + c0);
            #pragma unroll
            for (int u = 0; u < 8; ++u)
                *(short8*)&hs[row][c0 + u*8] = src[u];
        }
        __syncthreads();

        f32x4 acc[4][4];
        #pragma unroll
        for (int mt = 0; mt < 4; ++mt)
            #pragma unroll
            for (int ct = 0; ct < 4; ++ct)
                acc[mt][ct] = (f32x4){0.f,0.f,0.f,0.f};

        const short8* bb8 = (const short8*)dwP + ((size_t)vb*8*16 + wv*4)*64 + lane;
        short8 Bf[3][4];
        #define LDB_EM(slot_, kk) { \
            Bf[slot_][0] = bb8[((kk)*16 + 0)*64]; \
            Bf[slot_][1] = bb8[((kk)*16 + 1)*64]; \
            Bf[slot_][2] = bb8[((kk)*16 + 2)*64]; \
            Bf[slot_][3] = bb8[((kk)*16 + 3)*64]; }
        LDB_EM(0, 0)
        LDB_EM(1, 1)
        #pragma unroll
        for (int ks = 0; ks < 8; ++ks) {
            if (ks < 6) LDB_EM((ks+2)%3, ks+2)
            short8 a[4];
            #pragma unroll
            for (int mt = 0; mt < 4; ++mt)
                a[mt] = *(const short8*)&hs[mt*16 + l15][ks*32 + q*8];
            #pragma unroll
            for (int mt = 0; mt < 4; ++mt)
                #pragma unroll
                for (int ct = 0; ct < 4; ++ct)
                    acc[mt][ct] = __builtin_amdgcn_mfma_f32_16x16x32_bf16(a[mt], Bf[ks%3][ct], acc[mt][ct], 0,0,0);
        }
        #undef LDB_EM

        int vcol[4]; bool vok[4];
        #pragma unroll
        for (int ct = 0; ct < 4; ++ct) {
            int v = vb*256 + wv*64 + l15*4 + ct;
            vok[ct] = (v < Vv);
            vcol[ct] = v < Vv ? v : Vv-1;
        }
        #pragma unroll
        for (int ct = 0; ct < 4; ++ct) {
            if (vok[ct]) {
                float db = dec_b[vcol[ct]];
                #pragma unroll
                for (int mt = 0; mt < 4; ++mt)
                    #pragma unroll
                    for (int reg = 0; reg < 4; ++reg)
                        acc[mt][ct][reg] += db;
            } else {
                #pragma unroll
                for (int mt = 0; mt < 4; ++mt)
                    #pragma unroll
                    for (int reg = 0; reg < 4; ++reg)
                        acc[mt][ct][reg] = -1e30f;   // exp -> 0
            }
        }
        #pragma unroll
        for (int mt = 0; mt < 4; ++mt) {
            #pragma unroll
            for (int reg = 0; reg < 4; ++reg) {
                int k = kg*64 + mt*16 + q*4 + reg;
                u32x2 p;
                p.x = f2bf2(acc[mt][0][reg], acc[mt][1][reg]);
                p.y = f2bf2(acc[mt][2][reg], acc[mt][3][reg]);
                *(u32x2*)(E2 + (size_t)k*VPAD + vb*256 + wv*64 + l15*4) = p;
            }
        }
        // plain exp-sum over this wave's 64 cols (logits bounded; no max needed)
        #pragma unroll
        for (int mt = 0; mt < 4; ++mt) {
            #pragma unroll
            for (int reg = 0; reg < 4; ++reg) {
                float s = (__expf(acc[mt][0][reg]) + __expf(acc[mt][1][reg]))
                        + (__expf(acc[mt][2][reg]) + __expf(acc[mt][3][reg]));
                s += __shfl_xor(s, 1);
                s += __shfl_xor(s, 2);
                s += __shfl_xor(s, 4);
                s += __shfl_xor(s, 8);
                if (l15 == 0) {
                    int k = kg*64 + mt*16 + q*4 + reg;
                    part1[(size_t)(vb*4 + wv)*256 + k] = s;
                }
            }
        }
        return;
    }

    // ================= TRANS path =================
    int tr_id = bid - EMB;
    if (tr_id >= NTR) return;
    short (*th)[520]   = sm.tr.th;
    float (*musig)[2]  = sm.tr.musig;
    float (*lsep)[32][2] = sm.tr.lsep;
    int r0 = tr_id * 32;

    {
        const float4* bias0 = (const float4*)tm_bias;
        const float4* bias1 = (const float4*)(tm_bias + 256);
        float4 c0 = bias0[lane], c1 = bias1[lane];
        int i0a[8], i1a[8];
        #pragma unroll
        for (int i = 0; i < 8; ++i) {
            int r = r0 + wv*8 + i; if (r >= NROWS) r = NROWS - 1;
            i0a[i] = r / KP1; i1a[i] = r - i0a[i]*KP1;
        }
        #define ROWBODY(i, A0, B0, T0, A1, B1, T1) { \
            int row = wv*8 + (i); \
            float v0 = (T0).x + fmaxf((A0).x+(B0).x+c0.x, 0.f); \
            float v1 = (T0).y + fmaxf((A0).y+(B0).y+c0.y, 0.f); \
            float v2 = (T0).z + fmaxf((A0).z+(B0).z+c0.z, 0.f); \
            float v3 = (T0).w + fmaxf((A0).w+(B0).w+c0.w, 0.f); \
            float v4 = (T1).x + fmaxf((A1).x+(B1).x+c1.x, 0.f); \
            float v5 = (T1).y + fmaxf((A1).y+(B1).y+c1.y, 0.f); \
            float v6 = (T1).z + fmaxf((A1).z+(B1).z+c1.z, 0.f); \
            float v7 = (T1).w + fmaxf((A1).w+(B1).w+c1.w, 0.f); \
            u32x2 p0; p0.x = bfpack(v0, v1); p0.y = bfpack(v2, v3); \
            u32x2 p1; p1.x = bfpack(v4, v5); p1.y = bfpack(v6, v7); \
            *(u32x2*)&th[row][lane*4]       = p0; \
            *(u32x2*)&th[row][256 + lane*4] = p1; \
            float s  = ((v0+v1)+(v2+v3)) + ((v4+v5)+(v6+v7)); \
            float ss = ((v0*v0+v1*v1)+(v2*v2+v3*v3)) + ((v4*v4+v5*v5)+(v6*v6+v7*v7)); \
            _Pragma("unroll") \
            for (int d = 1; d < 64; d <<= 1) { \
                s  += __shfl_xor(s, d); \
                ss += __shfl_xor(ss, d); \
            } \
            if (lane == 0) { \
                float mu = s * (1.f/MD); \
                musig[row][0] = mu; \
                musig[row][1] = rsqrtf(ss*(1.f/MD) - mu*mu + EPSf); \
            } }

        if (i0a[0] == i0a[7]) {
            float4 A0 = ((const float4*)(P0 + (size_t)i0a[0]*MD))[lane];
            float4 A1 = ((const float4*)(P0 + (size_t)i0a[0]*MD + 256))[lane];
            float4 T0 = ((const float4*)(tlembs + (size_t)i0a[0]*Dd))[lane];
            #pragma unroll
            for (int i = 0; i < 8; ++i) {
                float4 b0 = ((const float4*)(P1 + (size_t)i1a[i]*MD))[lane];
                float4 b1 = ((const float4*)(P1 + (size_t)i1a[i]*MD + 256))[lane];
                float4 t1 = ((const float4*)(tlembs + (size_t)i1a[i]*Dd))[lane];
                ROWBODY(i, A0, b0, T0, A1, b1, t1)
            }
        } else {
            #pragma unroll
            for (int i = 0; i < 8; ++i) {
                float4 A0 = ((const float4*)(P0 + (size_t)i0a[i]*MD))[lane];
                float4 A1 = ((const float4*)(P0 + (size_t)i0a[i]*MD + 256))[lane];
                float4 T0 = ((const float4*)(tlembs + (size_t)i0a[i]*Dd))[lane];
                float4 b0 = ((const float4*)(P1 + (size_t)i1a[i]*MD))[lane];
                float4 b1 = ((const float4*)(P1 + (size_t)i1a[i]*MD + 256))[lane];
                float4 t1 = ((const float4*)(tlembs + (size_t)i1a[i]*Dd))[lane];
                ROWBODY(i, A0, b0, T0, A1, b1, t1)
            }
        }
        #undef ROWBODY
    }
    __syncthreads();

    f32x4 acc[2][4];
    #pragma unroll
    for (int rt = 0; rt < 2; ++rt)
        #pragma unroll
        for (int ct = 0; ct < 4; ++ct)
            acc[rt][ct] = (f32x4){0.f, 0.f, 0.f, 0.f};
    const short* bb = tdwg_bf + (size_t)wv*32768 + (size_t)lane*8;
    short8 Bf[3][4];
    #define LDB_TR(slot_, kk) { const short* nxt = bb + (size_t)(kk)*2048; \
        Bf[slot_][0] = *(const short8*)(nxt); \
        Bf[slot_][1] = *(const short8*)(nxt + 512); \
        Bf[slot_][2] = *(const short8*)(nxt + 1024); \
        Bf[slot_][3] = *(const short8*)(nxt + 1536); }
    LDB_TR(0, 0)
    LDB_TR(1, 1)
    #pragma unroll
    for (int ks = 0; ks < 16; ++ks) {
        if (ks < 14) LDB_TR((ks+2)%3, ks+2)
        int ko = ks*32 + q*8;
        short8 a0 = *(const short8*)&th[ 0 + l15][ko];
        short8 a1 = *(const short8*)&th[16 + l15][ko];
        acc[0][0] = __builtin_amdgcn_mfma_f32_16x16x32_bf16(a0, Bf[ks%3][0], acc[0][0], 0,0,0);
        acc[1][0] = __builtin_amdgcn_mfma_f32_16x16x32_bf16(a1, Bf[ks%3][0], acc[1][0], 0,0,0);
        acc[0][1] = __builtin_amdgcn_mfma_f32_16x16x32_bf16(a0, Bf[ks%3][1], acc[0][1], 0,0,0);
        acc[1][1] = __builtin_amdgcn_mfma_f32_16x16x32_bf16(a1, Bf[ks%3][1], acc[1][1], 0,0,0);
        acc[0][2] = __builtin_amdgcn_mfma_f32_16x16x32_bf16(a0, Bf[ks%3][2], acc[0][2], 0,0,0);
        acc[1][2] = __builtin_amdgcn_mfma_f32_16x16x32_bf16(a1, Bf[ks%3][2], acc[1][2], 0,0,0);
        acc[0][3] = __builtin_amdgcn_mfma_f32_16x16x32_bf16(a0, Bf[ks%3][3], acc[0][3], 0,0,0);
        acc[1][3] = __builtin_amdgcn_mfma_f32_16x16x32_bf16(a1, Bf[ks%3][3], acc[1][3], 0,0,0);
    }
    #undef LDB_TR

    float4 Gc = *(const float4*)(Gt + wv*64 + l15*4);
    float4 Bc = *(const float4*)(Bt + wv*64 + l15*4);
    #pragma unroll
    for (int rt = 0; rt < 2; ++rt) {
        #pragma unroll
        for (int reg = 0; reg < 4; ++reg) {
            int rw = rt*16 + q*4 + reg;
            float mu = musig[rw][0], rs = musig[rw][1];
            float e0 = rs*(acc[rt][0][reg] - mu*Gc.x) + Bc.x;
            float e1 = rs*(acc[rt][1][reg] - mu*Gc.y) + Bc.y;
            float e2 = rs*(acc[rt][2][reg] - mu*Gc.z) + Bc.z;
            float e3 = rs*(acc[rt][3][reg] - mu*Gc.w) + Bc.w;
            long r = (long)r0 + rw;
            if (r < NROWS) {
                u32x2 p;
                p.x = f2bf2(e0, e1);
                p.y = f2bf2(e2, e3);
                *(u32x2*)(Td + (size_t)r*Kst + wv*64 + l15*4) = p;
            }
            float m = fmaxf(fmaxf(e0, e1), fmaxf(e2, e3));
            m = fmaxf(m, __shfl_xor(m, 1));
            m = fmaxf(m, __shfl_xor(m, 2));
            m = fmaxf(m, __shfl_xor(m, 4));
            m = fmaxf(m, __shfl_xor(m, 8));
            float s = __expf(e0 - m) + __expf(e1 - m) + __expf(e2 - m) + __expf(e3 - m);
            s += __shfl_xor(s, 1);
            s += __shfl_xor(s, 2);
            s += __shfl_xor(s, 4);
            s += __shfl_xor(s, 8);
            if (l15 == 0) {
                lsep[wv][rw][0] = m;
                lsep[wv][rw][1] = s;
            }
        }
    }
    __syncthreads();
    if (tid < 32) {
        int r = r0 + tid;
        if (r < NROWS) {
            float m0 = lsep[0][tid][0], m1 = lsep[1][tid][0];
            float m2 = lsep[2][tid][0], m3 = lsep[3][tid][0];
            float mg = fmaxf(fmaxf(m0, m1), fmaxf(m2, m3));
            float s = lsep[0][tid][1]*__expf(m0-mg) + lsep[1][tid][1]*__expf(m1-mg)
                    + lsep[2][tid][1]*__expf(m2-mg) + lsep[3][tid][1]*__expf(m3-mg);
            lse_t[r] = mg + logf(s);
        }
    }
}

// ---------------- K_gather6: fused comb + gather + fin (3rd and last launch) ----------------
// 64 blocks. Prologue: each block column-sums part1[784][256] (coalesced) -> log -> LDS.
// Main: wave w owns b = blk*4 + w; lane handles 8 t; full-wave reduce; plain store.
__global__ __launch_bounds__(256) void k_gather6(
    const int* __restrict__ x, const int* __restrict__ z,
    const unsigned short* __restrict__ E2, const float* __restrict__ part1,
    const unsigned short* __restrict__ Td, const float* __restrict__ lse_t,
    float* __restrict__ out)
{
    __shared__ float lemp[4][256];
    __shared__ float lem[256];
    int tid = threadIdx.x, lane = tid & 63, w = tid >> 6;

    {
        const f32x4* p4 = (const f32x4*)part1;   // [784][64] f32x4 rows
        f32x4 s4 = (f32x4){0.f,0.f,0.f,0.f};
        int j0 = w*196;
        #pragma unroll 4
        for (int j = 0; j < 196; ++j) {
            f32x4 v = p4[(size_t)(j0 + j)*64 + lane];
            s4.x += v.x; s4.y += v.y; s4.z += v.z; s4.w += v.w;
        }
        *(f32x4*)&lemp[w][lane*4] = s4;
    }
    __syncthreads();
    lem[tid] = logf((lemp[0][tid] + lemp[1][tid]) + (lemp[2][tid] + lemp[3][tid]));
    __syncthreads();

    int b = blockIdx.x*4 + w;
    float accv = 0.f;
    #pragma unroll
    for (int u = 0; u < 8; ++u) {
        int t = u*64 + lane;
        int zc = z[t*Bb + b];
        int xv = x[t*Bb + b];
        int i0 = (t >= 2) ? z[(t-2)*Bb + b] : Kst;
        int i1 = (t >= 1) ? z[(t-1)*Bb + b] : Kst;
        int lin = i0*KP1 + i1;
        accv += bf2f(E2[(size_t)zc*VPAD + xv]) - lem[zc]
              + bf2f(Td[(size_t)lin*Kst + zc]) - lse_t[lin];
    }
    #pragma unroll
    for (int d = 1; d < 64; d <<= 1)
        accv += __shfl_xor(accv, d);
    if (lane == 0) out[b] = accv;
}

extern "C" void kernel_launch(void* const* d_in, const int* in_sizes, int n_in,
                              void* d_out, int out_size, void* d_ws, size_t ws_size,
                              hipStream_t stream)
{
    const int*   x       = (const int*)  d_in[0];
    const int*   z       = (const int*)  d_in[1];
    const float* lembs   = (const float*)d_in[2];
    const float* tlembs  = (const float*)d_in[3];
    const float* dec_W   = (const float*)d_in[4];
    const float* dec_b   = (const float*)d_in[5];
    const float* em_W    = (const float*)d_in[6];
    const float* em_bias = (const float*)d_in[7];
    const float* em_g    = (const float*)d_in[8];
    const float* em_beta = (const float*)d_in[9];
    const float* td_W    = (const float*)d_in[10];
    const float* td_b    = (const float*)d_in[11];
    const float* tm_W    = (const float*)d_in[12];
    const float* tm_bias = (const float*)d_in[13];
    const float* tn_g    = (const float*)d_in[14];
    const float* tn_beta = (const float*)d_in[15];
    float* out = (float*)d_out;

    float* ws     = (float*)d_ws;
    float* P0     = ws;                    // 131584
    float* P1     = P0 + 131584;           // 131584
    float* part1  = P1 + 131584;           // 784*256 = 200704
    float* lse_t  = part1 + 200704;        // 66052
    float* Gt     = lse_t + 66052;         // 256
    float* Bt     = Gt + 256;              // 256
    unsigned short* tdwg_bf = (unsigned short*)(Bt + 256);      // 131072 ushort (fragment layout)
    unsigned short* h_bf   = tdwg_bf + 131072;                  // 65536 ushort
    unsigned short* E2     = h_bf + 65536;                      // 256*50176 ushort (25.7MB)
    unsigned short* Td     = E2 + (size_t)Kst*VPAD;             // 66049*256 ushort (33.8MB)
    unsigned short* dwP    = Td + (size_t)NROWS*Kst;            // 50176*256 ushort (25.7MB)

    k_hP<<<108 + 784, 256, 0, stream>>>(lembs, em_W, em_bias, em_g, em_beta, h_bf,
                                        tlembs, tm_W, P0, P1,
                                        td_W, tn_g, tn_beta, td_b, tdwg_bf, Gt, Bt,
                                        dec_W, dwP);
    k_emtrans<<<EMB + NTR, 256, 0, stream>>>(
        dwP, dec_b, h_bf, part1, E2,
        tlembs, P0, P1, tm_bias, (const short*)tdwg_bf, Gt, Bt, lse_t, Td);
    k_gather6<<<64, 256, 0, stream>>>(x, z, E2, part1, Td, lse_t, out);
}

// Round 10
// 203.623 us; speedup vs baseline: 1.0808x; 1.0808x over previous
//
#include <hip/hip_runtime.h>

#define Kst 256
#define Dd 256
#define Vv 50000
#define VPAD 50176
#define Tt 512
#define Bb 256
#define KP1 257
#define MD 512
#define NROWS (KP1*KP1)   // 66049
#define EPSf 1e-5f

#define VB2 196           // vocab blocks (256 v each)
#define NP1 (VB2*4)       // 784 part1 rows
#define NTR ((NROWS+31)/32)  // 2065 trans tiles
#define EMB 800           // em block ids [0,800): xcd-bijective (bid%8 = xcd)

typedef __attribute__((ext_vector_type(8))) short short8;
typedef __attribute__((ext_vector_type(4))) float f32x4;
typedef __attribute__((ext_vector_type(4))) unsigned u32x4;
typedef __attribute__((ext_vector_type(2))) unsigned u32x2;

__device__ __forceinline__ unsigned short f2bf(float f) {
    unsigned u = __builtin_bit_cast(unsigned, f);
    unsigned r = (u + 0x7fffu + ((u >> 16) & 1u)) >> 16;
    return (unsigned short)r;
}
__device__ __forceinline__ float bf2f(unsigned short u) {
    return __builtin_bit_cast(float, ((unsigned)u) << 16);
}
// truncating pack (MFMA inputs only)
__device__ __forceinline__ unsigned bfpack(float lo, float hi) {
    return __builtin_amdgcn_perm(__builtin_bit_cast(unsigned, hi),
                                 __builtin_bit_cast(unsigned, lo), 0x07060302u);
}
// rounding pack (stores feeding final outputs)
__device__ __forceinline__ unsigned f2bf2(float lo, float hi) {
    return (unsigned)f2bf(lo) | ((unsigned)f2bf(hi) << 16);
}

// ---------------- K_hP: preprocessing (unchanged from round 9) ----------------
union HPU {
    struct { short ta[32][264]; float lsep[4][32][2]; float musig[32][2]; } g;
    struct { short pl[64][266]; } p;
};

__global__ __launch_bounds__(256) void k_hP(
    const float* __restrict__ lembs, const float* __restrict__ em_W,
    const float* __restrict__ em_bias, const float* __restrict__ em_g,
    const float* __restrict__ em_beta, unsigned short* __restrict__ h_bf,
    const float* __restrict__ tlembs, const float* __restrict__ tm_W,
    float* __restrict__ P0, float* __restrict__ P1,
    const float* __restrict__ td_W, const float* __restrict__ tn_g,
    const float* __restrict__ tn_beta, const float* __restrict__ td_b,
    unsigned short* __restrict__ tdwg_bf, float* __restrict__ Gt,
    float* __restrict__ Bt, const float* __restrict__ dec_W,
    unsigned short* __restrict__ dwP)
{
    __shared__ HPU su;
    int bid = blockIdx.x;
    int tid = threadIdx.x, lane = tid & 63, wv = tid >> 6;
    int l15 = lane & 15, q = lane >> 4;

    if (bid >= 108) {
        int pb = bid - 108;                // 0..783
        int vb2 = pb >> 2, c = pb & 3;
        short (*pl)[266] = su.p.pl;
        int base_row = vb2*256 + c*64;
        #pragma unroll 4
        for (int i = 0; i < 16; ++i) {
            int row = wv*16 + i;
            int grow = base_row + row; if (grow > Vv-1) grow = Vv-1;
            float4 f = ((const float4*)(dec_W + (size_t)grow*Dd))[lane];
            u32x2 w; w.x = bfpack(f.x, f.y); w.y = bfpack(f.z, f.w);
            *(u32x2*)&pl[row][lane*4] = w;
        }
        __syncthreads();
        #pragma unroll
        for (int i = 0; i < 8; ++i) {
            short8 val = *(const short8*)&pl[(lane & 15)*4 + wv][i*32 + (lane >> 4)*8];
            *(short8*)(dwP + ((size_t)vb2*8192 + (size_t)i*1024
                              + (c*4 + wv)*64 + lane)*8) = val;
        }
        return;
    }

    if (bid >= 44) {
        int c = (bid - 44)*4 + wv;
        const float4* w4 = (const float4*)(td_W + (size_t)c*MD);
        const float4* g4 = (const float4*)tn_g;
        const float4* b4 = (const float4*)tn_beta;
        float sg = 0.f, sb = 0.f;
        short8 o;
        #pragma unroll
        for (int u = 0; u < 2; ++u) {
            int j4 = lane*2 + u;
            float4 w = w4[j4], g = g4[j4], bt = b4[j4];
            sg += w.x*g.x + w.y*g.y + w.z*g.z + w.w*g.w;
            sb += w.x*bt.x + w.y*bt.y + w.z*bt.z + w.w*bt.w;
            o[u*4+0] = (short)f2bf(w.x*g.x);
            o[u*4+1] = (short)f2bf(w.y*g.y);
            o[u*4+2] = (short)f2bf(w.z*g.z);
            o[u*4+3] = (short)f2bf(w.w*g.w);
        }
        {
            int wvv = c >> 6, l15v = (c >> 2) & 15, ctv = c & 3;
            int ksv = lane >> 2, qv = lane & 3;
            *(short8*)(tdwg_bf +
                ((((size_t)wvv*16 + ksv)*4 + ctv)*64 + (qv*16 + l15v))*8) = o;
        }
        #pragma unroll
        for (int dd = 32; dd > 0; dd >>= 1) {
            sg += __shfl_xor(sg, dd);
            sb += __shfl_xor(sb, dd);
        }
        if (lane == 0) { Gt[c] = sg; Bt[c] = sb + td_b[c]; }
        return;
    }

    short (*ta)[264] = su.g.ta;
    float (*lsep)[32][2] = su.g.lsep;
    float (*musig)[2] = su.g.musig;

    int job, r0, cb, koff, BK;
    const float* Arow; const float* Brow;
    if (bid < 8) {
        job = 0; r0 = bid*32; cb = 0; koff = 0; BK = Dd;
        Arow = lembs; Brow = em_W;
    } else {
        int b2 = bid - 8;
        int half = b2 / 18;
        int b3 = b2 % 18;
        job = 1 + half;
        r0 = (b3 >> 1) * 32;
        cb = (b3 & 1) * 256;
        koff = half * 256; BK = MD;
        Arow = tlembs; Brow = tm_W;
    }

    {
        int row = tid >> 3, seg = (tid & 7) * 32;
        int r = r0 + row;
        if (r > 256) r = 256;
        const float4* s4 = (const float4*)(Arow + (size_t)r*Dd + seg);
        #pragma unroll
        for (int u = 0; u < 4; ++u) {
            float4 f0 = s4[u*2], f1 = s4[u*2+1];
            u32x4 pk;
            pk.x = bfpack(f0.x, f0.y);
            pk.y = bfpack(f0.z, f0.w);
            pk.z = bfpack(f1.x, f1.y);
            pk.w = bfpack(f1.z, f1.w);
            *(short8*)&ta[row][seg + u*8] = __builtin_bit_cast(short8, pk);
        }
    }
    __syncthreads();

    const float* bptr[4];
    #pragma unroll
    for (int ct = 0; ct < 4; ++ct) {
        int j = cb + wv*64 + ct*16 + l15;
        bptr[ct] = Brow + (size_t)j*BK + koff + q*8;
    }
    f32x4 acc[2][4];
    #pragma unroll
    for (int rt = 0; rt < 2; ++rt)
        #pragma unroll
        for (int ct = 0; ct < 4; ++ct)
            acc[rt][ct] = (f32x4){0.f,0.f,0.f,0.f};
    for (int ks = 0; ks < 8; ++ks) {
        short8 a0 = *(const short8*)&ta[ 0 + l15][ks*32 + q*8];
        short8 a1 = *(const short8*)&ta[16 + l15][ks*32 + q*8];
        short8 b[4];
        #pragma unroll
        for (int ct = 0; ct < 4; ++ct) {
            float4 f0 = *(const float4*)(bptr[ct] + ks*32);
            float4 f1 = *(const float4*)(bptr[ct] + ks*32 + 4);
            u32x4 pk;
            pk.x = bfpack(f0.x, f0.y);
            pk.y = bfpack(f0.z, f0.w);
            pk.z = bfpack(f1.x, f1.y);
            pk.w = bfpack(f1.z, f1.w);
            b[ct] = __builtin_bit_cast(short8, pk);
        }
        #pragma unroll
        for (int ct = 0; ct < 4; ++ct) {
            acc[0][ct] = __builtin_amdgcn_mfma_f32_16x16x32_bf16(a0, b[ct], acc[0][ct], 0,0,0);
            acc[1][ct] = __builtin_amdgcn_mfma_f32_16x16x32_bf16(a1, b[ct], acc[1][ct], 0,0,0);
        }
    }

    if (job != 0) {
        float* Pd = (job == 1) ? P0 : P1;
        #pragma unroll
        for (int rt = 0; rt < 2; ++rt) {
            #pragma unroll
            for (int reg = 0; reg < 4; ++reg) {
                int r = r0 + rt*16 + q*4 + reg;
                if (r < KP1) {
                    float* dst = Pd + (size_t)r*MD + cb + wv*64;
                    #pragma unroll
                    for (int ct = 0; ct < 4; ++ct)
                        dst[ct*16 + l15] = acc[rt][ct][reg];
                }
            }
        }
        return;
    }

    float bias_c[4];
    #pragma unroll
    for (int ct = 0; ct < 4; ++ct)
        bias_c[ct] = em_bias[wv*64 + ct*16 + l15];
    #pragma unroll
    for (int rt = 0; rt < 2; ++rt) {
        #pragma unroll
        for (int reg = 0; reg < 4; ++reg) {
            int r = r0 + rt*16 + q*4 + reg;
            #pragma unroll
            for (int ct = 0; ct < 4; ++ct) {
                float lv = lembs[(size_t)r*Dd + wv*64 + ct*16 + l15];
                acc[rt][ct][reg] = lv + fmaxf(acc[rt][ct][reg] + bias_c[ct], 0.f);
            }
        }
    }
    #pragma unroll
    for (int rt = 0; rt < 2; ++rt) {
        #pragma unroll
        for (int reg = 0; reg < 4; ++reg) {
            float s  = ((acc[rt][0][reg] + acc[rt][1][reg]) + (acc[rt][2][reg] + acc[rt][3][reg]));
            float ss = ((acc[rt][0][reg]*acc[rt][0][reg] + acc[rt][1][reg]*acc[rt][1][reg])
                      + (acc[rt][2][reg]*acc[rt][2][reg] + acc[rt][3][reg]*acc[rt][3][reg]));
            s  += __shfl_xor(s, 1);  ss += __shfl_xor(ss, 1);
            s  += __shfl_xor(s, 2);  ss += __shfl_xor(ss, 2);
            s  += __shfl_xor(s, 4);  ss += __shfl_xor(ss, 4);
            s  += __shfl_xor(s, 8);  ss += __shfl_xor(ss, 8);
            if (l15 == 0) {
                int rw = rt*16 + q*4 + reg;
                lsep[wv][rw][0] = s;
                lsep[wv][rw][1] = ss;
            }
        }
    }
    __syncthreads();
    if (tid < 32) {
        float s  = (lsep[0][tid][0] + lsep[1][tid][0]) + (lsep[2][tid][0] + lsep[3][tid][0]);
        float ss = (lsep[0][tid][1] + lsep[1][tid][1]) + (lsep[2][tid][1] + lsep[3][tid][1]);
        float mu = s * (1.f/Dd);
        musig[tid][0] = mu;
        musig[tid][1] = rsqrtf(ss*(1.f/Dd) - mu*mu + EPSf);
    }
    __syncthreads();
    float gl[4], bl[4];
    #pragma unroll
    for (int ct = 0; ct < 4; ++ct) {
        gl[ct] = em_g[wv*64 + ct*16 + l15];
        bl[ct] = em_beta[wv*64 + ct*16 + l15];
    }
    #pragma unroll
    for (int rt = 0; rt < 2; ++rt) {
        #pragma unroll
        for (int reg = 0; reg < 4; ++reg) {
            int rw = rt*16 + q*4 + reg;
            int r = r0 + rw;
            float mu = musig[rw][0], rs = musig[rw][1];
            unsigned short* dst = h_bf + (size_t)r*Dd + wv*64;
            #pragma unroll
            for (int ct = 0; ct < 4; ++ct)
                dst[ct*16 + l15] = f2bf((acc[rt][ct][reg] - mu)*rs*gl[ct] + bl[ct]);
        }
    }
}

// ---------------- K_emtrans: FUSED; trans staging now 1-deep pipelined ----------------
union SMemU {
    struct { short hs[64][264]; } em;
    struct { short th[32][520]; float musig[32][2]; float lsep[4][32][2]; } tr;
};

__global__ __launch_bounds__(256, 4) void k_emtrans(
    const unsigned short* __restrict__ dwP, const float* __restrict__ dec_b,
    const unsigned short* __restrict__ h_bf, float* __restrict__ part1,
    unsigned short* __restrict__ E2,
    const float* __restrict__ tlembs, const float* __restrict__ P0,
    const float* __restrict__ P1, const float* __restrict__ tm_bias,
    const short* __restrict__ tdwg_bf, const float* __restrict__ Gt,
    const float* __restrict__ Bt, float* __restrict__ lse_t,
    unsigned short* __restrict__ Td)
{
    __shared__ SMemU sm;
    int bid = blockIdx.x;
    int tid = threadIdx.x, lane = tid & 63, wv = tid >> 6;
    int l15 = lane & 15, q = lane >> 4;

    if (bid < EMB) {
        // ================= EM path =================
        int xcd = bid & 7, slot = bid >> 3;
        int g2 = slot >> 2, kg = slot & 3;
        int vb = g2*8 + xcd;
        if (vb >= VB2) return;
        short (*hs)[264] = sm.em.hs;

        {
            int row = tid >> 2, c0 = (tid & 3) * 64;
            const short8* src = (const short8*)(h_bf + (size_t)(kg*64 + row)*Dd + c0);
            #pragma unroll
            for (int u = 0; u < 8; ++u)
                *(short8*)&hs[row][c0 + u*8] = src[u];
        }
        __syncthreads();

        f32x4 acc[4][4];
        #pragma unroll
        for (int mt = 0; mt < 4; ++mt)
            #pragma unroll
            for (int ct = 0; ct < 4; ++ct)
                acc[mt][ct] = (f32x4){0.f,0.f,0.f,0.f};

        const short8* bb8 = (const short8*)dwP + ((size_t)vb*8*16 + wv*4)*64 + lane;
        short8 Bf[3][4];
        #define LDB_EM(slot_, kk) { \
            Bf[slot_][0] = bb8[((kk)*16 + 0)*64]; \
            Bf[slot_][1] = bb8[((kk)*16 + 1)*64]; \
            Bf[slot_][2] = bb8[((kk)*16 + 2)*64]; \
            Bf[slot_][3] = bb8[((kk)*16 + 3)*64]; }
        LDB_EM(0, 0)
        LDB_EM(1, 1)
        #pragma unroll
        for (int ks = 0; ks < 8; ++ks) {
            if (ks < 6) LDB_EM((ks+2)%3, ks+2)
            short8 a[4];
            #pragma unroll
            for (int mt = 0; mt < 4; ++mt)
                a[mt] = *(const short8*)&hs[mt*16 + l15][ks*32 + q*8];
            #pragma unroll
            for (int mt = 0; mt < 4; ++mt)
                #pragma unroll
                for (int ct = 0; ct < 4; ++ct)
                    acc[mt][ct] = __builtin_amdgcn_mfma_f32_16x16x32_bf16(a[mt], Bf[ks%3][ct], acc[mt][ct], 0,0,0);
        }
        #undef LDB_EM

        int vcol[4]; bool vok[4];
        #pragma unroll
        for (int ct = 0; ct < 4; ++ct) {
            int v = vb*256 + wv*64 + l15*4 + ct;
            vok[ct] = (v < Vv);
            vcol[ct] = v < Vv ? v : Vv-1;
        }
        #pragma unroll
        for (int ct = 0; ct < 4; ++ct) {
            if (vok[ct]) {
                float db = dec_b[vcol[ct]];
                #pragma unroll
                for (int mt = 0; mt < 4; ++mt)
                    #pragma unroll
                    for (int reg = 0; reg < 4; ++reg)
                        acc[mt][ct][reg] += db;
            } else {
                #pragma unroll
                for (int mt = 0; mt < 4; ++mt)
                    #pragma unroll
                    for (int reg = 0; reg < 4; ++reg)
                        acc[mt][ct][reg] = -1e30f;   // exp -> 0
            }
        }
        #pragma unroll
        for (int mt = 0; mt < 4; ++mt) {
            #pragma unroll
            for (int reg = 0; reg < 4; ++reg) {
                int k = kg*64 + mt*16 + q*4 + reg;
                u32x2 p;
                p.x = f2bf2(acc[mt][0][reg], acc[mt][1][reg]);
                p.y = f2bf2(acc[mt][2][reg], acc[mt][3][reg]);
                *(u32x2*)(E2 + (size_t)k*VPAD + vb*256 + wv*64 + l15*4) = p;
            }
        }
        // plain exp-sum over this wave's 64 cols (logits bounded; no max needed)
        #pragma unroll
        for (int mt = 0; mt < 4; ++mt) {
            #pragma unroll
            for (int reg = 0; reg < 4; ++reg) {
                float s = (__expf(acc[mt][0][reg]) + __expf(acc[mt][1][reg]))
                        + (__expf(acc[mt][2][reg]) + __expf(acc[mt][3][reg]));
                s += __shfl_xor(s, 1);
                s += __shfl_xor(s, 2);
                s += __shfl_xor(s, 4);
                s += __shfl_xor(s, 8);
                if (l15 == 0) {
                    int k = kg*64 + mt*16 + q*4 + reg;
                    part1[(size_t)(vb*4 + wv)*256 + k] = s;
                }
            }
        }
        return;
    }

    // ================= TRANS path =================
    int tr_id = bid - EMB;
    if (tr_id >= NTR) return;
    short (*th)[520]   = sm.tr.th;
    float (*musig)[2]  = sm.tr.musig;
    float (*lsep)[32][2] = sm.tr.lsep;
    int r0 = tr_id * 32;

    {
        const float4* bias0 = (const float4*)tm_bias;
        const float4* bias1 = (const float4*)(tm_bias + 256);
        float4 c0 = bias0[lane], c1 = bias1[lane];
        int i0a[8], i1a[8];
        #pragma unroll
        for (int i = 0; i < 8; ++i) {
            int r = r0 + wv*8 + i; if (r >= NROWS) r = NROWS - 1;
            i0a[i] = r / KP1; i1a[i] = r - i0a[i]*KP1;
        }
        #define ROWBODY(i, A0, B0, T0, A1, B1, T1) { \
            int row = wv*8 + (i); \
            float v0 = (T0).x + fmaxf((A0).x+(B0).x+c0.x, 0.f); \
            float v1 = (T0).y + fmaxf((A0).y+(B0).y+c0.y, 0.f); \
            float v2 = (T0).z + fmaxf((A0).z+(B0).z+c0.z, 0.f); \
            float v3 = (T0).w + fmaxf((A0).w+(B0).w+c0.w, 0.f); \
            float v4 = (T1).x + fmaxf((A1).x+(B1).x+c1.x, 0.f); \
            float v5 = (T1).y + fmaxf((A1).y+(B1).y+c1.y, 0.f); \
            float v6 = (T1).z + fmaxf((A1).z+(B1).z+c1.z, 0.f); \
            float v7 = (T1).w + fmaxf((A1).w+(B1).w+c1.w, 0.f); \
            u32x2 p0; p0.x = bfpack(v0, v1); p0.y = bfpack(v2, v3); \
            u32x2 p1; p1.x = bfpack(v4, v5); p1.y = bfpack(v6, v7); \
            *(u32x2*)&th[row][lane*4]       = p0; \
            *(u32x2*)&th[row][256 + lane*4] = p1; \
            float s  = ((v0+v1)+(v2+v3)) + ((v4+v5)+(v6+v7)); \
            float ss = ((v0*v0+v1*v1)+(v2*v2+v3*v3)) + ((v4*v4+v5*v5)+(v6*v6+v7*v7)); \
            _Pragma("unroll") \
            for (int d = 1; d < 64; d <<= 1) { \
                s  += __shfl_xor(s, d); \
                ss += __shfl_xor(ss, d); \
            } \
            if (lane == 0) { \
                float mu = s * (1.f/MD); \
                musig[row][0] = mu; \
                musig[row][1] = rsqrtf(ss*(1.f/MD) - mu*mu + EPSf); \
            } }

        if (i0a[0] == i0a[7]) {
            // uniform i0: hoist A/T for i0; pipeline the 3 per-row loads
            float4 A0 = ((const float4*)(P0 + (size_t)i0a[0]*MD))[lane];
            float4 A1 = ((const float4*)(P0 + (size_t)i0a[0]*MD + 256))[lane];
            float4 T0 = ((const float4*)(tlembs + (size_t)i0a[0]*Dd))[lane];
            float4 b0 = ((const float4*)(P1 + (size_t)i1a[0]*MD))[lane];
            float4 b1 = ((const float4*)(P1 + (size_t)i1a[0]*MD + 256))[lane];
            float4 t1 = ((const float4*)(tlembs + (size_t)i1a[0]*Dd))[lane];
            #pragma unroll
            for (int i = 0; i < 8; ++i) {
                float4 nb0, nb1, nt1;
                if (i < 7) {
                    nb0 = ((const float4*)(P1 + (size_t)i1a[i+1]*MD))[lane];
                    nb1 = ((const float4*)(P1 + (size_t)i1a[i+1]*MD + 256))[lane];
                    nt1 = ((const float4*)(tlembs + (size_t)i1a[i+1]*Dd))[lane];
                }
                ROWBODY(i, A0, b0, T0, A1, b1, t1)
                b0 = nb0; b1 = nb1; t1 = nt1;
            }
        } else {
            // non-uniform: pipeline all 6 per-row loads
            float4 A0 = ((const float4*)(P0 + (size_t)i0a[0]*MD))[lane];
            float4 A1 = ((const float4*)(P0 + (size_t)i0a[0]*MD + 256))[lane];
            float4 T0 = ((const float4*)(tlembs + (size_t)i0a[0]*Dd))[lane];
            float4 b0 = ((const float4*)(P1 + (size_t)i1a[0]*MD))[lane];
            float4 b1 = ((const float4*)(P1 + (size_t)i1a[0]*MD + 256))[lane];
            float4 t1 = ((const float4*)(tlembs + (size_t)i1a[0]*Dd))[lane];
            #pragma unroll
            for (int i = 0; i < 8; ++i) {
                float4 nA0, nA1, nT0, nb0, nb1, nt1;
                if (i < 7) {
                    nA0 = ((const float4*)(P0 + (size_t)i0a[i+1]*MD))[lane];
                    nA1 = ((const float4*)(P0 + (size_t)i0a[i+1]*MD + 256))[lane];
                    nT0 = ((const float4*)(tlembs + (size_t)i0a[i+1]*Dd))[lane];
                    nb0 = ((const float4*)(P1 + (size_t)i1a[i+1]*MD))[lane];
                    nb1 = ((const float4*)(P1 + (size_t)i1a[i+1]*MD + 256))[lane];
                    nt1 = ((const float4*)(tlembs + (size_t)i1a[i+1]*Dd))[lane];
                }
                ROWBODY(i, A0, b0, T0, A1, b1, t1)
                A0 = nA0; A1 = nA1; T0 = nT0; b0 = nb0; b1 = nb1; t1 = nt1;
            }
        }
        #undef ROWBODY
    }
    __syncthreads();

    f32x4 acc[2][4];
    #pragma unroll
    for (int rt = 0; rt < 2; ++rt)
        #pragma unroll
        for (int ct = 0; ct < 4; ++ct)
            acc[rt][ct] = (f32x4){0.f, 0.f, 0.f, 0.f};
    const short* bb = tdwg_bf + (size_t)wv*32768 + (size_t)lane*8;
    short8 Bf[3][4];
    #define LDB_TR(slot_, kk) { const short* nxt = bb + (size_t)(kk)*2048; \
        Bf[slot_][0] = *(const short8*)(nxt); \
        Bf[slot_][1] = *(const short8*)(nxt + 512); \
        Bf[slot_][2] = *(const short8*)(nxt + 1024); \
        Bf[slot_][3] = *(const short8*)(nxt + 1536); }
    LDB_TR(0, 0)
    LDB_TR(1, 1)
    #pragma unroll
    for (int ks = 0; ks < 16; ++ks) {
        if (ks < 14) LDB_TR((ks+2)%3, ks+2)
        int ko = ks*32 + q*8;
        short8 a0 = *(const short8*)&th[ 0 + l15][ko];
        short8 a1 = *(const short8*)&th[16 + l15][ko];
        acc[0][0] = __builtin_amdgcn_mfma_f32_16x16x32_bf16(a0, Bf[ks%3][0], acc[0][0], 0,0,0);
        acc[1][0] = __builtin_amdgcn_mfma_f32_16x16x32_bf16(a1, Bf[ks%3][0], acc[1][0], 0,0,0);
        acc[0][1] = __builtin_amdgcn_mfma_f32_16x16x32_bf16(a0, Bf[ks%3][1], acc[0][1], 0,0,0);
        acc[1][1] = __builtin_amdgcn_mfma_f32_16x16x32_bf16(a1, Bf[ks%3][1], acc[1][1], 0,0,0);
        acc[0][2] = __builtin_amdgcn_mfma_f32_16x16x32_bf16(a0, Bf[ks%3][2], acc[0][2], 0,0,0);
        acc[1][2] = __builtin_amdgcn_mfma_f32_16x16x32_bf16(a1, Bf[ks%3][2], acc[1][2], 0,0,0);
        acc[0][3] = __builtin_amdgcn_mfma_f32_16x16x32_bf16(a0, Bf[ks%3][3], acc[0][3], 0,0,0);
        acc[1][3] = __builtin_amdgcn_mfma_f32_16x16x32_bf16(a1, Bf[ks%3][3], acc[1][3], 0,0,0);
    }
    #undef LDB_TR

    float4 Gc = *(const float4*)(Gt + wv*64 + l15*4);
    float4 Bc = *(const float4*)(Bt + wv*64 + l15*4);
    #pragma unroll
    for (int rt = 0; rt < 2; ++rt) {
        #pragma unroll
        for (int reg = 0; reg < 4; ++reg) {
            int rw = rt*16 + q*4 + reg;
            float mu = musig[rw][0], rs = musig[rw][1];
            float e0 = rs*(acc[rt][0][reg] - mu*Gc.x) + Bc.x;
            float e1 = rs*(acc[rt][1][reg] - mu*Gc.y) + Bc.y;
            float e2 = rs*(acc[rt][2][reg] - mu*Gc.z) + Bc.z;
            float e3 = rs*(acc[rt][3][reg] - mu*Gc.w) + Bc.w;
            long r = (long)r0 + rw;
            if (r < NROWS) {
                u32x2 p;
                p.x = f2bf2(e0, e1);
                p.y = f2bf2(e2, e3);
                *(u32x2*)(Td + (size_t)r*Kst + wv*64 + l15*4) = p;
            }
            float m = fmaxf(fmaxf(e0, e1), fmaxf(e2, e3));
            m = fmaxf(m, __shfl_xor(m, 1));
            m = fmaxf(m, __shfl_xor(m, 2));
            m = fmaxf(m, __shfl_xor(m, 4));
            m = fmaxf(m, __shfl_xor(m, 8));
            float s = __expf(e0 - m) + __expf(e1 - m) + __expf(e2 - m) + __expf(e3 - m);
            s += __shfl_xor(s, 1);
            s += __shfl_xor(s, 2);
            s += __shfl_xor(s, 4);
            s += __shfl_xor(s, 8);
            if (l15 == 0) {
                lsep[wv][rw][0] = m;
                lsep[wv][rw][1] = s;
            }
        }
    }
    __syncthreads();
    if (tid < 32) {
        int r = r0 + tid;
        if (r < NROWS) {
            float m0 = lsep[0][tid][0], m1 = lsep[1][tid][0];
            float m2 = lsep[2][tid][0], m3 = lsep[3][tid][0];
            float mg = fmaxf(fmaxf(m0, m1), fmaxf(m2, m3));
            float s = lsep[0][tid][1]*__expf(m0-mg) + lsep[1][tid][1]*__expf(m1-mg)
                    + lsep[2][tid][1]*__expf(m2-mg) + lsep[3][tid][1]*__expf(m3-mg);
            lse_t[r] = mg + logf(s);
        }
    }
}

// ---------------- K_lse8: parallel partial column-sums of part1 (8 blocks) ----------------
__global__ __launch_bounds__(256) void k_lse8(
    const float* __restrict__ part1, float* __restrict__ lpart)
{
    __shared__ float lemp[4][256];
    int tid = threadIdx.x, lane = tid & 63, w = tid >> 6;
    const f32x4* p4 = (const f32x4*)part1;   // rows of 64 f32x4
    f32x4 s4 = (f32x4){0.f,0.f,0.f,0.f};
    int j0 = blockIdx.x * 98;
    for (int j = j0 + w; j < j0 + 98; j += 4) {
        f32x4 v = p4[(size_t)j*64 + lane];
        s4.x += v.x; s4.y += v.y; s4.z += v.z; s4.w += v.w;
    }
    *(f32x4*)&lemp[w][lane*4] = s4;
    __syncthreads();
    lpart[blockIdx.x*256 + tid] = (lemp[0][tid] + lemp[1][tid]) + (lemp[2][tid] + lemp[3][tid]);
}

// ---------------- K_gather7: b-coalesced, rolling z regs, 8 t per thread ----------------
__global__ __launch_bounds__(256) void k_gather7(
    const int* __restrict__ x, const int* __restrict__ z,
    const unsigned short* __restrict__ E2, const float* __restrict__ lpart,
    const unsigned short* __restrict__ Td, const float* __restrict__ lse_t,
    float* __restrict__ gpart)
{
    __shared__ float lem[256];
    int tid = threadIdx.x;
    {
        float s = 0.f;
        #pragma unroll
        for (int r = 0; r < 8; ++r) s += lpart[r*256 + tid];
        lem[tid] = logf(s);
    }
    __syncthreads();

    int b = tid;
    int t0 = blockIdx.x * 8;
    int zm1 = (t0 >= 1) ? z[(t0-1)*Bb + b] : Kst;
    int zm2 = (t0 >= 2) ? z[(t0-2)*Bb + b] : Kst;
    float accv = 0.f;
    #pragma unroll
    for (int u = 0; u < 8; ++u) {
        int t = t0 + u;
        int zc = z[t*Bb + b];
        int xv = x[t*Bb + b];
        int lin = zm2*KP1 + zm1;
        accv += bf2f(E2[(size_t)zc*VPAD + xv]) - lem[zc]
              + bf2f(Td[(size_t)lin*Kst + zc]) - lse_t[lin];
        zm2 = zm1; zm1 = zc;
    }
    gpart[blockIdx.x*Bb + b] = accv;
}

// ---------------- K_fin: out[b] = sum of 64 t-chunk partials ----------------
__global__ __launch_bounds__(256) void k_fin(
    const float* __restrict__ gpart, float* __restrict__ out)
{
    int b = threadIdx.x;
    float s = 0.f;
    #pragma unroll 8
    for (int r = 0; r < 64; ++r)
        s += gpart[r*Bb + b];
    out[b] = s;
}

extern "C" void kernel_launch(void* const* d_in, const int* in_sizes, int n_in,
                              void* d_out, int out_size, void* d_ws, size_t ws_size,
                              hipStream_t stream)
{
    const int*   x       = (const int*)  d_in[0];
    const int*   z       = (const int*)  d_in[1];
    const float* lembs   = (const float*)d_in[2];
    const float* tlembs  = (const float*)d_in[3];
    const float* dec_W   = (const float*)d_in[4];
    const float* dec_b   = (const float*)d_in[5];
    const float* em_W    = (const float*)d_in[6];
    const float* em_bias = (const float*)d_in[7];
    const float* em_g    = (const float*)d_in[8];
    const float* em_beta = (const float*)d_in[9];
    const float* td_W    = (const float*)d_in[10];
    const float* td_b    = (const float*)d_in[11];
    const float* tm_W    = (const float*)d_in[12];
    const float* tm_bias = (const float*)d_in[13];
    const float* tn_g    = (const float*)d_in[14];
    const float* tn_beta = (const float*)d_in[15];
    float* out = (float*)d_out;

    float* ws     = (float*)d_ws;
    float* P0     = ws;                    // 131584
    float* P1     = P0 + 131584;           // 131584
    float* part1  = P1 + 131584;           // 784*256 = 200704
    float* lpart  = part1 + 200704;        // 8*256 = 2048
    float* gpart  = lpart + 2048;          // 64*256 = 16384
    float* lse_t  = gpart + 16384;         // 66052
    float* Gt     = lse_t + 66052;         // 256
    float* Bt     = Gt + 256;              // 256
    unsigned short* tdwg_bf = (unsigned short*)(Bt + 256);      // 131072 ushort (fragment layout)
    unsigned short* h_bf   = tdwg_bf + 131072;                  // 65536 ushort
    unsigned short* E2     = h_bf + 65536;                      // 256*50176 ushort (25.7MB)
    unsigned short* Td     = E2 + (size_t)Kst*VPAD;             // 66049*256 ushort (33.8MB)
    unsigned short* dwP    = Td + (size_t)NROWS*Kst;            // 50176*256 ushort (25.7MB)

    k_hP<<<108 + 784, 256, 0, stream>>>(lembs, em_W, em_bias, em_g, em_beta, h_bf,
                                        tlembs, tm_W, P0, P1,
                                        td_W, tn_g, tn_beta, td_b, tdwg_bf, Gt, Bt,
                                        dec_W, dwP);
    k_emtrans<<<EMB + NTR, 256, 0, stream>>>(
        dwP, dec_b, h_bf, part1, E2,
        tlembs, P0, P1, tm_bias, (const short*)tdwg_bf, Gt, Bt, lse_t, Td);
    k_lse8<<<8, 256, 0, stream>>>(part1, lpart);
    k_gather7<<<64, 256, 0, stream>>>(x, z, E2, lpart, Td, lse_t, gpart);
    k_fin<<<1, 256, 0, stream>>>(gpart, out);
}